// Round 8
// baseline (152.030 us; speedup 1.0000x reference)
//
#include <hip/hip_runtime.h>
#include <hip/hip_bf16.h>

#define BB 4
#define SS 2048
#define HH 576
#define NHD 9
#define NKVH 3
#define HDIM 64

using s8v  = __attribute__((ext_vector_type(8))) short;
using f4v  = __attribute__((ext_vector_type(4))) float;
using f16v = __attribute__((ext_vector_type(16))) float;

__device__ __forceinline__ unsigned short f2bf(float f) {
  union { float f; unsigned u; } x; x.f = f;
  unsigned r = x.u + 0x7fffu + ((x.u >> 16) & 1u);
  return (unsigned short)(r >> 16);
}

__device__ __forceinline__ unsigned pk2bf(float lo, float hi) {
  union { __hip_bfloat162 h; unsigned u; } c;
  c.h = __float22bfloat162_rn(make_float2(lo, hi));
  return c.u;
}

__device__ __forceinline__ float fexp2(float x) {
#if __has_builtin(__builtin_amdgcn_exp2f)
  return __builtin_amdgcn_exp2f(x);
#else
  return exp2f(x);
#endif
}

// Q pre-scale: (1/sqrt(64)) * log2(e) -> softmax runs in exp2 domain
#define QSCALE 0.1803368867f

// ---------------- kernel 1: cast hidden_states fp32 -> bf16 ----------------
__global__ void cast_x_kernel(const float* __restrict__ hs, unsigned short* __restrict__ xb) {
  long i = (long)blockIdx.x * blockDim.x + threadIdx.x;
  long base = i * 4;
  float4 v = *(const float4*)(hs + base);
  ushort4 o;
  o.x = f2bf(v.x); o.y = f2bf(v.y); o.z = f2bf(v.z); o.w = f2bf(v.w);
  *(ushort4*)(xb + base) = o;
}

// ------------- kernel 2: pack weights -> bf16, transposed [n][k] -----------
__global__ void pack_w_kernel(const float* __restrict__ wq, const float* __restrict__ wk,
                              const float* __restrict__ wv, const float* __restrict__ wo,
                              unsigned short* __restrict__ wqkvt, unsigned short* __restrict__ wot) {
  int i = blockIdx.x * blockDim.x + threadIdx.x;
  if (i < 960 * 576) {
    int n = i / 576, k = i % 576;
    float val;
    if (n < 576)      val = wq[k * 576 + n];
    else if (n < 768) val = wk[k * 192 + (n - 576)];
    else              val = wv[k * 192 + (n - 768)];
    wqkvt[n * 576 + k] = f2bf(val);
  } else {
    int j = i - 960 * 576;
    int n = j / 576, k = j % 576;
    wot[n * 576 + k] = f2bf(wo[k * 576 + n]);
  }
}

// ======================= tiled GEMM core (shared fn) =======================
#define LDSBUF 12288

__device__ __forceinline__ void gemm_tile_core(char* lds,
    const unsigned short* __restrict__ Ag,
    const unsigned short* __restrict__ Bg,
    int tid, f4v acc[2][4])
{
  const int lane = tid & 63, wid = tid >> 6;
  const int l15 = lane & 15, hi = lane >> 4;
  const int r = tid >> 2, p = tid & 3;

  const unsigned short* sA0 = Ag + (long)r * 576 + p * 8;
  const unsigned short* sA1 = sA0 + (long)64 * 576;
  const unsigned short* sB  = Bg + (long)r * 576 + p * 8;
  const int dA0 = r * 64 + ((p ^ (r & 3)) * 16);
  const int dA1 = dA0 + 4096;
  const int dB  = 8192 + dA0;

  const int roff = (wid * 32 + l15) * 64 + ((hi ^ (l15 & 3)) * 16);
  const int boff = 8192 + l15 * 64 + ((hi ^ (l15 & 3)) * 16);

  s8v rA0 = *(const s8v*)(sA0);
  s8v rA1 = *(const s8v*)(sA1);
  s8v rB  = *(const s8v*)(sB);
  *(s8v*)(lds + dA0) = rA0;
  *(s8v*)(lds + dA1) = rA1;
  *(s8v*)(lds + dB)  = rB;
  __syncthreads();

  int cur = 0;
  for (int t = 0; t < 18; ++t) {
    if (t < 17) {
      rA0 = *(const s8v*)(sA0 + (t + 1) * 32);
      rA1 = *(const s8v*)(sA1 + (t + 1) * 32);
      rB  = *(const s8v*)(sB  + (t + 1) * 32);
    }
    {
      char* buf = lds + cur * LDSBUF;
      s8v af0 = *(const s8v*)(buf + roff);
      s8v af1 = *(const s8v*)(buf + roff + 16 * 64);
      s8v bf0 = *(const s8v*)(buf + boff);
      s8v bf1 = *(const s8v*)(buf + boff + 16 * 64);
      s8v bf2 = *(const s8v*)(buf + boff + 32 * 64);
      s8v bf3 = *(const s8v*)(buf + boff + 48 * 64);
      acc[0][0] = __builtin_amdgcn_mfma_f32_16x16x32_bf16(af0, bf0, acc[0][0], 0, 0, 0);
      acc[0][1] = __builtin_amdgcn_mfma_f32_16x16x32_bf16(af0, bf1, acc[0][1], 0, 0, 0);
      acc[0][2] = __builtin_amdgcn_mfma_f32_16x16x32_bf16(af0, bf2, acc[0][2], 0, 0, 0);
      acc[0][3] = __builtin_amdgcn_mfma_f32_16x16x32_bf16(af0, bf3, acc[0][3], 0, 0, 0);
      acc[1][0] = __builtin_amdgcn_mfma_f32_16x16x32_bf16(af1, bf0, acc[1][0], 0, 0, 0);
      acc[1][1] = __builtin_amdgcn_mfma_f32_16x16x32_bf16(af1, bf1, acc[1][1], 0, 0, 0);
      acc[1][2] = __builtin_amdgcn_mfma_f32_16x16x32_bf16(af1, bf2, acc[1][2], 0, 0, 0);
      acc[1][3] = __builtin_amdgcn_mfma_f32_16x16x32_bf16(af1, bf3, acc[1][3], 0, 0, 0);
    }
    if (t < 17) {
      char* nbuf = lds + (cur ^ 1) * LDSBUF;
      *(s8v*)(nbuf + dA0) = rA0;
      *(s8v*)(nbuf + dA1) = rA1;
      *(s8v*)(nbuf + dB)  = rB;
    }
    __syncthreads();
    cur ^= 1;
  }
}

// ---- kernel 3: QKV GEMM (tiled) + fused RoPE; writes Q,K,[Vt] bf16 --------
__global__ __launch_bounds__(256) void qkv_gemm_kernel(
    const unsigned short* __restrict__ xb, const unsigned short* __restrict__ wt,
    const float* __restrict__ rot,
    unsigned short* __restrict__ qbuf, unsigned short* __restrict__ kbuf,
    unsigned short* __restrict__ vtbuf)
{
  __shared__ char lds[2 * LDSBUF];
  const int tid = threadIdx.x;
  const int lane = tid & 63, wid = tid >> 6;
  const int l15 = lane & 15, hi = lane >> 4;
  const int m0 = blockIdx.x * 128;
  const int g  = blockIdx.y;   // 0..8 Q, 9..11 K, 12..14 V

  f4v acc[2][4] = {};
  gemm_tile_core(lds, xb + (long)m0 * 576, wt + (long)(g * 64) * 576, tid, acc);

  const int rbase = m0 + wid * 32;
#pragma unroll
  for (int fm = 0; fm < 2; ++fm) {
#pragma unroll
    for (int rr = 0; rr < 4; ++rr) {
      const int row = rbase + fm * 16 + hi * 4 + rr;
      const int b = row >> 11, s = row & (SS - 1);
      if (g < 12) {
#pragma unroll
        for (int fn = 0; fn < 2; ++fn) {
          const int d = fn * 16 + l15;
          const float sn = rot[s * 64 + d];
          const float cs = rot[s * 64 + 32 + d];
          const float x1 = acc[fm][fn][rr];
          const float x2 = acc[fm][fn + 2][rr];
          acc[fm][fn][rr]     = x1 * cs - x2 * sn;
          acc[fm][fn + 2][rr] = x1 * sn + x2 * cs;
        }
      }
      if (g < 9) {
        unsigned short* dst = qbuf + ((long)((b * NHD + g) * SS + s)) * HDIM;
#pragma unroll
        for (int fn = 0; fn < 4; ++fn)
          dst[fn * 16 + l15] = f2bf(acc[fm][fn][rr] * QSCALE);
      } else if (g < 12) {
        unsigned short* dst = kbuf + ((long)((b * NKVH + (g - 9)) * SS + s)) * HDIM;
#pragma unroll
        for (int fn = 0; fn < 4; ++fn)
          dst[fn * 16 + l15] = f2bf(acc[fm][fn][rr]);
      } else {
        const int h = g - 12;
#pragma unroll
        for (int fn = 0; fn < 4; ++fn) {
          const int d = fn * 16 + l15;
          vtbuf[((long)((b * NKVH + h) * HDIM + d)) * SS + s] = f2bf(acc[fm][fn][rr]);
        }
      }
    }
  }
}

// --------------- kernel 5: output projection (tiled) -> fp32 ---------------
__global__ __launch_bounds__(256) void out_gemm_kernel(
    const unsigned short* __restrict__ ob, const unsigned short* __restrict__ wot,
    float* __restrict__ out)
{
  __shared__ char lds[2 * LDSBUF];
  const int tid = threadIdx.x;
  const int lane = tid & 63, wid = tid >> 6;
  const int l15 = lane & 15, hi = lane >> 4;
  const int m0 = blockIdx.x * 128;
  const int n0 = blockIdx.y * 64;

  f4v acc[2][4] = {};
  gemm_tile_core(lds, ob + (long)m0 * 576, wot + (long)n0 * 576, tid, acc);

  const int rbase = m0 + wid * 32;
#pragma unroll
  for (int fm = 0; fm < 2; ++fm)
#pragma unroll
    for (int rr = 0; rr < 4; ++rr) {
      const int row = rbase + fm * 16 + hi * 4 + rr;
#pragma unroll
      for (int fn = 0; fn < 4; ++fn)
        out[(long)row * 576 + n0 + fn * 16 + l15] = acc[fm][fn][rr];
    }
}

// ------ kernel 4: flash, 32x32x16 swapped QK^T + 4-way block split-KV ------
// XCD-aware decode: hw bid -> xcd = bid&7 (round-robin assumption, m157);
// each XCD gets a contiguous logical range L = xcd*288 + bid/8 covering
// <= 2 KV panels (panel = (b,hkv), 0.5 MB) -> K/V stay in local 4MB L2.
// Within panel: within = (63-qs)*3 + h3 (descending work first).
// V loads hoisted above QK^T MFMAs (use-distance ~ full softmax + QK).
__global__ __launch_bounds__(256, 4) void flash32_kernel(
    const unsigned short* __restrict__ qbuf, const unsigned short* __restrict__ kbuf,
    const unsigned short* __restrict__ vtbuf, unsigned short* __restrict__ obuf)
{
  __shared__ float Osh[4][64 * 32];   // [wave][d][q] f32
  __shared__ float mlsh[4][2][32];    // [wave][m|l][q]

  const int tid = threadIdx.x;
  const int lane = tid & 63, wv = tid >> 6;
  const int l31 = lane & 31, hi = lane >> 5;

  // XCD-local panel decode (2304 = 8 * 288; 288 = 1.5 panels of 192)
  const int i = blockIdx.x;
  const int L = (i & 7) * 288 + (i >> 3);
  const int panel = L / 192;          // 0..11 = b*3 + hkv
  const int within = L % 192;
  const int qs = 63 - within / 3;
  const int h3 = within % 3;
  const int b = panel / 3, hkv = panel % 3;
  const int h = hkv * 3 + h3;
  const int q0 = qs * 32;

  const int nt = qs + 1;
  const int ts = (nt * wv) >> 2;
  const int te = (nt * (wv + 1)) >> 2;

  const unsigned short* Q  = qbuf + ((long)(b * NHD + h) * SS) * HDIM;
  const unsigned short* K  = kbuf + ((long)(b * NKVH + hkv) * SS) * HDIM;
  const unsigned short* Vt = vtbuf + ((long)(b * NKVH + hkv) * HDIM) * SS;

  f16v accO0 = {}, accO1 = {};
  float m_run = -1e30f, l_run = 0.f;

  if (te > ts) {
    s8v qf[4];
#pragma unroll
    for (int ks = 0; ks < 4; ++ks)
      qf[ks] = *(const s8v*)(Q + (long)(q0 + l31) * HDIM + ks * 16 + hi * 8);

    s8v kf[4];
#pragma unroll
    for (int ks = 0; ks < 4; ++ks)
      kf[ks] = *(const s8v*)(K + (long)(ts * 32 + l31) * HDIM + ks * 16 + hi * 8);

    for (int t = ts; t < te; ++t) {
      const int kv0 = t * 32;
      // V loads FIRST: use-distance spans QK^T + softmax (~500 cyc)
      s8v vf00 = *(const s8v*)(Vt + (long)(l31) * SS      + kv0 + hi * 8);
      s8v vf01 = *(const s8v*)(Vt + (long)(l31) * SS      + kv0 + 16 + hi * 8);
      s8v vf10 = *(const s8v*)(Vt + (long)(32 + l31) * SS + kv0 + hi * 8);
      s8v vf11 = *(const s8v*)(Vt + (long)(32 + l31) * SS + kv0 + 16 + hi * 8);

      f16v S = {};
      S = __builtin_amdgcn_mfma_f32_32x32x16_bf16(kf[0], qf[0], S, 0, 0, 0);
      S = __builtin_amdgcn_mfma_f32_32x32x16_bf16(kf[1], qf[1], S, 0, 0, 0);
      S = __builtin_amdgcn_mfma_f32_32x32x16_bf16(kf[2], qf[2], S, 0, 0, 0);
      S = __builtin_amdgcn_mfma_f32_32x32x16_bf16(kf[3], qf[3], S, 0, 0, 0);

      {  // K(t+1) prefetch: use-distance spans softmax + PV
        const unsigned short* Kn = K + (long)(kv0 + 32 + l31) * HDIM;
#pragma unroll
        for (int ks = 0; ks < 4; ++ks)
          kf[ks] = *(const s8v*)(Kn + ks * 16 + hi * 8);
      }

      if (kv0 == q0) {  // boundary tile: keep iff kv row <= q col
#pragma unroll
        for (int r = 0; r < 16; ++r) {
          const int row = (r & 3) + 8 * (r >> 2) + 4 * hi;
          S[r] = (row <= l31) ? S[r] : -1e30f;
        }
      }
      float mloc = S[0];
#pragma unroll
      for (int r = 1; r < 16; ++r) mloc = fmaxf(mloc, S[r]);
      mloc = fmaxf(mloc, __shfl_xor(mloc, 32));
      if (__any(mloc > m_run + 8.f)) {   // defer-max (THR=8, exp2 domain)
        const float mnew = fmaxf(m_run, mloc);
        const float corr = fexp2(m_run - mnew);
        m_run = mnew;
        l_run *= corr;
#pragma unroll
        for (int r = 0; r < 16; ++r) { accO0[r] *= corr; accO1[r] *= corr; }
      }
      float p[16], sloc = 0.f;
#pragma unroll
      for (int r = 0; r < 16; ++r) {
        p[r] = fexp2(S[r] - m_run);
        sloc += p[r];
      }
      sloc += __shfl_xor(sloc, 32);
      l_run += sloc;

      const unsigned u0 = pk2bf(p[0],  p[1]),  u1 = pk2bf(p[2],  p[3]);
      const unsigned u2 = pk2bf(p[4],  p[5]),  u3 = pk2bf(p[6],  p[7]);
      const unsigned u4 = pk2bf(p[8],  p[9]),  u5 = pk2bf(p[10], p[11]);
      const unsigned u6 = pk2bf(p[12], p[13]), u7 = pk2bf(p[14], p[15]);
      const unsigned e0 = __shfl_xor(u0, 32), e1 = __shfl_xor(u1, 32);
      const unsigned e2 = __shfl_xor(u2, 32), e3 = __shfl_xor(u3, 32);
      const unsigned e4 = __shfl_xor(u4, 32), e5 = __shfl_xor(u5, 32);
      const unsigned e6 = __shfl_xor(u6, 32), e7 = __shfl_xor(u7, 32);
      const bool hih = (hi != 0);
      union { unsigned u[4]; s8v v; } P0, P1;
      P0.u[0] = hih ? e2 : u0;  P0.u[1] = hih ? e3 : u1;
      P0.u[2] = hih ? u2 : e0;  P0.u[3] = hih ? u3 : e1;
      P1.u[0] = hih ? e6 : u4;  P1.u[1] = hih ? e7 : u5;
      P1.u[2] = hih ? u6 : e4;  P1.u[3] = hih ? u7 : e5;

      accO0 = __builtin_amdgcn_mfma_f32_32x32x16_bf16(vf00, P0.v, accO0, 0, 0, 0);
      accO0 = __builtin_amdgcn_mfma_f32_32x32x16_bf16(vf01, P1.v, accO0, 0, 0, 0);
      accO1 = __builtin_amdgcn_mfma_f32_32x32x16_bf16(vf10, P0.v, accO1, 0, 0, 0);
      accO1 = __builtin_amdgcn_mfma_f32_32x32x16_bf16(vf11, P1.v, accO1, 0, 0, 0);
    }
  }

  // ---- stage partials to LDS: O[d][q] (lanes stride-1 in q, conflict-free)
  {
    float* Ow = &Osh[wv][0];
#pragma unroll
    for (int g = 0; g < 4; ++g) {
#pragma unroll
      for (int j = 0; j < 4; ++j) {
        const int d0 = (g << 3) + (hi << 2) + j;
        Ow[d0 * 32 + l31]        = accO0[4 * g + j];
        Ow[(32 + d0) * 32 + l31] = accO1[4 * g + j];
      }
    }
    if (hi == 0) { mlsh[wv][0][l31] = m_run; mlsh[wv][1][l31] = l_run; }
  }
  __syncthreads();

  // ---- combine: thread (q = tid&31, d = (tid>>5)*8 .. +8)
  {
    const int q = tid & 31;
    const int d0 = (tid >> 5) * 8;
    float m[4], l[4];
#pragma unroll
    for (int w = 0; w < 4; ++w) { m[w] = mlsh[w][0][q]; l[w] = mlsh[w][1][q]; }
    const float M = fmaxf(fmaxf(m[0], m[1]), fmaxf(m[2], m[3]));
    float wg[4], L2 = 0.f;
#pragma unroll
    for (int w = 0; w < 4; ++w) { wg[w] = fexp2(m[w] - M); L2 += l[w] * wg[w]; }
    const float inv = 1.f / L2;
    union { unsigned short s[8]; ushort4 v[2]; } ou;
#pragma unroll
    for (int j = 0; j < 8; ++j) {
      const int d = d0 + j;
      const float o_ = Osh[0][d * 32 + q] * wg[0] + Osh[1][d * 32 + q] * wg[1]
                     + Osh[2][d * 32 + q] * wg[2] + Osh[3][d * 32 + q] * wg[3];
      ou.s[j] = f2bf(o_ * inv);
    }
    unsigned short* orow = obuf + (long)(b * SS + q0 + q) * HH + h * HDIM + d0;
    *(ushort4*)(orow)     = ou.v[0];
    *(ushort4*)(orow + 4) = ou.v[1];
  }
}

extern "C" void kernel_launch(void* const* d_in, const int* in_sizes, int n_in,
                              void* d_out, int out_size, void* d_ws, size_t ws_size,
                              hipStream_t stream) {
  const float* hs  = (const float*)d_in[0];
  const float* rot = (const float*)d_in[2];
  const float* wq  = (const float*)d_in[3];
  const float* wk  = (const float*)d_in[4];
  const float* wv  = (const float*)d_in[5];
  const float* wo  = (const float*)d_in[6];
  float* out = (float*)d_out;

  char* ws = (char*)d_ws;
  unsigned short* xb    = (unsigned short*)(ws + 0);          // 9,437,184
  unsigned short* wqkvt = (unsigned short*)(ws + 9437184);    // 1,105,920
  unsigned short* wot   = (unsigned short*)(ws + 10543104);   //   663,552
  unsigned short* qb    = (unsigned short*)(ws + 11206656);   // 9,437,184
  unsigned short* kb    = (unsigned short*)(ws + 20643840);   // 3,145,728
  unsigned short* vt    = (unsigned short*)(ws + 23789568);   // 3,145,728
  unsigned short* obuf  = (unsigned short*)(ws + 26935296);   // 9,437,184 -> 36,372,480

  cast_x_kernel<<<4608, 256, 0, stream>>>(hs, xb);
  pack_w_kernel<<<3456, 256, 0, stream>>>(wq, wk, wv, wo, wqkvt, wot);
  qkv_gemm_kernel<<<dim3(64, 15), 256, 0, stream>>>(xb, wqkvt, rot, qb, kb, vt);
  flash32_kernel<<<2304, 256, 0, stream>>>(qb, kb, vt, obuf);
  out_gemm_kernel<<<dim3(64, 9), 256, 0, stream>>>(obuf, wot, out);
}

// Round 9
// 106.260 us; speedup vs baseline: 1.4307x; 1.4307x over previous
//
#include <hip/hip_runtime.h>
#include <hip/hip_bf16.h>

#define BB 4
#define SS 2048
#define HH 576
#define NHD 9
#define NKVH 3
#define HDIM 64

using s8v  = __attribute__((ext_vector_type(8))) short;
using f4v  = __attribute__((ext_vector_type(4))) float;
using f16v = __attribute__((ext_vector_type(16))) float;

__device__ __forceinline__ unsigned short f2bf(float f) {
  union { float f; unsigned u; } x; x.f = f;
  unsigned r = x.u + 0x7fffu + ((x.u >> 16) & 1u);
  return (unsigned short)(r >> 16);
}

__device__ __forceinline__ unsigned pk2bf(float lo, float hi) {
  union { __hip_bfloat162 h; unsigned u; } c;
  c.h = __float22bfloat162_rn(make_float2(lo, hi));
  return c.u;
}

__device__ __forceinline__ float fexp2(float x) {
#if __has_builtin(__builtin_amdgcn_exp2f)
  return __builtin_amdgcn_exp2f(x);
#else
  return exp2f(x);
#endif
}

// Q pre-scale: (1/sqrt(64)) * log2(e) -> softmax runs in exp2 domain
#define QSCALE 0.1803368867f

// ---------------- kernel 1: cast hidden_states fp32 -> bf16 ----------------
__global__ void cast_x_kernel(const float* __restrict__ hs, unsigned short* __restrict__ xb) {
  long i = (long)blockIdx.x * blockDim.x + threadIdx.x;
  long base = i * 4;
  float4 v = *(const float4*)(hs + base);
  ushort4 o;
  o.x = f2bf(v.x); o.y = f2bf(v.y); o.z = f2bf(v.z); o.w = f2bf(v.w);
  *(ushort4*)(xb + base) = o;
}

// ------------- kernel 2: pack weights -> bf16, transposed [n][k] -----------
__global__ void pack_w_kernel(const float* __restrict__ wq, const float* __restrict__ wk,
                              const float* __restrict__ wv, const float* __restrict__ wo,
                              unsigned short* __restrict__ wqkvt, unsigned short* __restrict__ wot) {
  int i = blockIdx.x * blockDim.x + threadIdx.x;
  if (i < 960 * 576) {
    int n = i / 576, k = i % 576;
    float val;
    if (n < 576)      val = wq[k * 576 + n];
    else if (n < 768) val = wk[k * 192 + (n - 576)];
    else              val = wv[k * 192 + (n - 768)];
    wqkvt[n * 576 + k] = f2bf(val);
  } else {
    int j = i - 960 * 576;
    int n = j / 576, k = j % 576;
    wot[n * 576 + k] = f2bf(wo[k * 576 + n]);
  }
}

// ======================= tiled GEMM core (shared fn) =======================
#define LDSBUF 12288

__device__ __forceinline__ void gemm_tile_core(char* lds,
    const unsigned short* __restrict__ Ag,
    const unsigned short* __restrict__ Bg,
    int tid, f4v acc[2][4])
{
  const int lane = tid & 63, wid = tid >> 6;
  const int l15 = lane & 15, hi = lane >> 4;
  const int r = tid >> 2, p = tid & 3;

  const unsigned short* sA0 = Ag + (long)r * 576 + p * 8;
  const unsigned short* sA1 = sA0 + (long)64 * 576;
  const unsigned short* sB  = Bg + (long)r * 576 + p * 8;
  const int dA0 = r * 64 + ((p ^ (r & 3)) * 16);
  const int dA1 = dA0 + 4096;
  const int dB  = 8192 + dA0;

  const int roff = (wid * 32 + l15) * 64 + ((hi ^ (l15 & 3)) * 16);
  const int boff = 8192 + l15 * 64 + ((hi ^ (l15 & 3)) * 16);

  s8v rA0 = *(const s8v*)(sA0);
  s8v rA1 = *(const s8v*)(sA1);
  s8v rB  = *(const s8v*)(sB);
  *(s8v*)(lds + dA0) = rA0;
  *(s8v*)(lds + dA1) = rA1;
  *(s8v*)(lds + dB)  = rB;
  __syncthreads();

  int cur = 0;
  for (int t = 0; t < 18; ++t) {
    if (t < 17) {
      rA0 = *(const s8v*)(sA0 + (t + 1) * 32);
      rA1 = *(const s8v*)(sA1 + (t + 1) * 32);
      rB  = *(const s8v*)(sB  + (t + 1) * 32);
    }
    {
      char* buf = lds + cur * LDSBUF;
      s8v af0 = *(const s8v*)(buf + roff);
      s8v af1 = *(const s8v*)(buf + roff + 16 * 64);
      s8v bf0 = *(const s8v*)(buf + boff);
      s8v bf1 = *(const s8v*)(buf + boff + 16 * 64);
      s8v bf2 = *(const s8v*)(buf + boff + 32 * 64);
      s8v bf3 = *(const s8v*)(buf + boff + 48 * 64);
      acc[0][0] = __builtin_amdgcn_mfma_f32_16x16x32_bf16(af0, bf0, acc[0][0], 0, 0, 0);
      acc[0][1] = __builtin_amdgcn_mfma_f32_16x16x32_bf16(af0, bf1, acc[0][1], 0, 0, 0);
      acc[0][2] = __builtin_amdgcn_mfma_f32_16x16x32_bf16(af0, bf2, acc[0][2], 0, 0, 0);
      acc[0][3] = __builtin_amdgcn_mfma_f32_16x16x32_bf16(af0, bf3, acc[0][3], 0, 0, 0);
      acc[1][0] = __builtin_amdgcn_mfma_f32_16x16x32_bf16(af1, bf0, acc[1][0], 0, 0, 0);
      acc[1][1] = __builtin_amdgcn_mfma_f32_16x16x32_bf16(af1, bf1, acc[1][1], 0, 0, 0);
      acc[1][2] = __builtin_amdgcn_mfma_f32_16x16x32_bf16(af1, bf2, acc[1][2], 0, 0, 0);
      acc[1][3] = __builtin_amdgcn_mfma_f32_16x16x32_bf16(af1, bf3, acc[1][3], 0, 0, 0);
    }
    if (t < 17) {
      char* nbuf = lds + (cur ^ 1) * LDSBUF;
      *(s8v*)(nbuf + dA0) = rA0;
      *(s8v*)(nbuf + dA1) = rA1;
      *(s8v*)(nbuf + dB)  = rB;
    }
    __syncthreads();
    cur ^= 1;
  }
}

// ---- kernel 3: QKV GEMM (tiled) + fused RoPE; writes Q,K,[Vt] bf16 --------
__global__ __launch_bounds__(256) void qkv_gemm_kernel(
    const unsigned short* __restrict__ xb, const unsigned short* __restrict__ wt,
    const float* __restrict__ rot,
    unsigned short* __restrict__ qbuf, unsigned short* __restrict__ kbuf,
    unsigned short* __restrict__ vtbuf)
{
  __shared__ char lds[2 * LDSBUF];
  const int tid = threadIdx.x;
  const int lane = tid & 63, wid = tid >> 6;
  const int l15 = lane & 15, hi = lane >> 4;
  const int m0 = blockIdx.x * 128;
  const int g  = blockIdx.y;   // 0..8 Q, 9..11 K, 12..14 V

  f4v acc[2][4] = {};
  gemm_tile_core(lds, xb + (long)m0 * 576, wt + (long)(g * 64) * 576, tid, acc);

  const int rbase = m0 + wid * 32;
#pragma unroll
  for (int fm = 0; fm < 2; ++fm) {
#pragma unroll
    for (int rr = 0; rr < 4; ++rr) {
      const int row = rbase + fm * 16 + hi * 4 + rr;
      const int b = row >> 11, s = row & (SS - 1);
      if (g < 12) {
#pragma unroll
        for (int fn = 0; fn < 2; ++fn) {
          const int d = fn * 16 + l15;
          const float sn = rot[s * 64 + d];
          const float cs = rot[s * 64 + 32 + d];
          const float x1 = acc[fm][fn][rr];
          const float x2 = acc[fm][fn + 2][rr];
          acc[fm][fn][rr]     = x1 * cs - x2 * sn;
          acc[fm][fn + 2][rr] = x1 * sn + x2 * cs;
        }
      }
      if (g < 9) {
        unsigned short* dst = qbuf + ((long)((b * NHD + g) * SS + s)) * HDIM;
#pragma unroll
        for (int fn = 0; fn < 4; ++fn)
          dst[fn * 16 + l15] = f2bf(acc[fm][fn][rr] * QSCALE);
      } else if (g < 12) {
        unsigned short* dst = kbuf + ((long)((b * NKVH + (g - 9)) * SS + s)) * HDIM;
#pragma unroll
        for (int fn = 0; fn < 4; ++fn)
          dst[fn * 16 + l15] = f2bf(acc[fm][fn][rr]);
      } else {
        const int h = g - 12;
#pragma unroll
        for (int fn = 0; fn < 4; ++fn) {
          const int d = fn * 16 + l15;
          vtbuf[((long)((b * NKVH + h) * HDIM + d)) * SS + s] = f2bf(acc[fm][fn][rr]);
        }
      }
    }
  }
}

// --------------- kernel 5: output projection (tiled) -> fp32 ---------------
__global__ __launch_bounds__(256) void out_gemm_kernel(
    const unsigned short* __restrict__ ob, const unsigned short* __restrict__ wot,
    float* __restrict__ out)
{
  __shared__ char lds[2 * LDSBUF];
  const int tid = threadIdx.x;
  const int lane = tid & 63, wid = tid >> 6;
  const int l15 = lane & 15, hi = lane >> 4;
  const int m0 = blockIdx.x * 128;
  const int n0 = blockIdx.y * 64;

  f4v acc[2][4] = {};
  gemm_tile_core(lds, ob + (long)m0 * 576, wot + (long)n0 * 576, tid, acc);

  const int rbase = m0 + wid * 32;
#pragma unroll
  for (int fm = 0; fm < 2; ++fm)
#pragma unroll
    for (int rr = 0; rr < 4; ++rr) {
      const int row = rbase + fm * 16 + hi * 4 + rr;
#pragma unroll
      for (int fn = 0; fn < 4; ++fn)
        out[(long)row * 576 + n0 + fn * 16 + l15] = acc[fm][fn][rr];
    }
}

// ---- kernel 4: flash, LDS-staged K/V shared by 4 waves (guide §B port) ----
// Block = 256 thr = 4 waves; wave w owns q rows q0+w*32..+32 (full kv range,
// no split-KV). KVBLK=64 staged to LDS (K tile [64][64] + V tile [64][64]
// bf16, XOR-swizzled chunk^=(row&7), double-buffered = 32 KB). 2-phase
// pipeline: issue global loads(t+1) -> compute(t) from LDS -> ds_write(t+1)
// -> barrier. Causal guard per wave; barriers uniform.
__global__ __launch_bounds__(256, 4) void flash_lds_kernel(
    const unsigned short* __restrict__ qbuf, const unsigned short* __restrict__ kbuf,
    const unsigned short* __restrict__ vtbuf, unsigned short* __restrict__ obuf)
{
  __shared__ char lds[32768];
  const int tid = threadIdx.x;
  const int lane = tid & 63, w = tid >> 6;
  const int l31 = lane & 31, hi = lane >> 5;

  const int bid = blockIdx.x;               // 0..575
  const int qi = 15 - bid / 36;             // descending work
  const int bh = bid % 36;
  const int q0 = qi * 128;
  const int b = bh / NHD, h = bh % NHD;
  const int hkv = h / 3;
  const int nt = 2 * qi + 2;                // 64-kv tiles in [0, q0+128)
  const int qw0 = q0 + w * 32;              // this wave's q rows

  const unsigned short* Q  = qbuf + ((long)(b * NHD + h) * SS) * HDIM;
  const unsigned short* K  = kbuf + ((long)(b * NKVH + hkv) * SS) * HDIM;
  const unsigned short* Vt = vtbuf + ((long)(b * NKVH + hkv) * HDIM) * SS;

  // Q B-frags: col q = qw0+l31, k(d) = ks*16 + hi*8 + j
  s8v qf[4];
#pragma unroll
  for (int ks = 0; ks < 4; ++ks)
    qf[ks] = *(const s8v*)(Q + (long)(qw0 + l31) * HDIM + ks * 16 + hi * 8);

  // staging: thread -> (row sr, chunk-pair sc); 32B K + 32B V per thread/tile
  const int sr = tid >> 2, sc = tid & 3;
  const unsigned short* gK = K  + (long)sr * HDIM + sc * 16;
  const unsigned short* gV = Vt + (long)sr * SS   + sc * 16;
  const int swz = sr & 7;
  const int dK0 = sr * 128 + (((sc * 2)     ^ swz) * 16);
  const int dK1 = sr * 128 + (((sc * 2 + 1) ^ swz) * 16);

  f16v accO0 = {}, accO1 = {};
  float m_run = -1e30f, l_run = 0.f;

  // prologue: stage tile 0 into buf 0
  s8v k0 = *(const s8v*)(gK);
  s8v k1 = *(const s8v*)(gK + 8);
  s8v v0 = *(const s8v*)(gV);
  s8v v1 = *(const s8v*)(gV + 8);
  *(s8v*)(lds + dK0) = k0;
  *(s8v*)(lds + dK1) = k1;
  *(s8v*)(lds + 8192 + dK0) = v0;
  *(s8v*)(lds + 8192 + dK1) = v1;
  __syncthreads();

  const int rswz = l31 & 7;   // read-side swizzle (row&7 for both K and V rows)
  int cur = 0;
  for (int t = 0; t < nt; ++t) {
    const int kv0 = t * 64;
    if (t + 1 < nt) {  // issue next-tile global loads early (T14)
      k0 = *(const s8v*)(gK + (long)(kv0 + 64) * HDIM);
      k1 = *(const s8v*)(gK + (long)(kv0 + 64) * HDIM + 8);
      v0 = *(const s8v*)(gV + kv0 + 64);
      v1 = *(const s8v*)(gV + kv0 + 64 + 8);
    }
    char* Kb = lds + cur * 16384;
    char* Vb = Kb + 8192;
#pragma unroll
    for (int s = 0; s < 2; ++s) {
      const int kv0s = kv0 + s * 32;
      if (kv0s < qw0 + 32) {   // wave-uniform causal guard
        // K A-frags from LDS: row = s*32+l31, chunk = 2*ks+hi
        const int krow = (s * 32 + l31) * 128;
        s8v kf0 = *(const s8v*)(Kb + krow + (((0 + hi) ^ rswz) * 16));
        s8v kf1 = *(const s8v*)(Kb + krow + (((2 + hi) ^ rswz) * 16));
        s8v kf2 = *(const s8v*)(Kb + krow + (((4 + hi) ^ rswz) * 16));
        s8v kf3 = *(const s8v*)(Kb + krow + (((6 + hi) ^ rswz) * 16));

        f16v S = {};
        S = __builtin_amdgcn_mfma_f32_32x32x16_bf16(kf0, qf[0], S, 0, 0, 0);
        S = __builtin_amdgcn_mfma_f32_32x32x16_bf16(kf1, qf[1], S, 0, 0, 0);
        S = __builtin_amdgcn_mfma_f32_32x32x16_bf16(kf2, qf[2], S, 0, 0, 0);
        S = __builtin_amdgcn_mfma_f32_32x32x16_bf16(kf3, qf[3], S, 0, 0, 0);

        // V A-frags from LDS: rows d = l31 / 32+l31, kv chunks s*4 + {hi, 2+hi}
        const int vrow0 = l31 * 128, vrow1 = (32 + l31) * 128;
        const int vc = s * 4;
        s8v vf00 = *(const s8v*)(Vb + vrow0 + (((vc + hi)     ^ rswz) * 16));
        s8v vf01 = *(const s8v*)(Vb + vrow0 + (((vc + 2 + hi) ^ rswz) * 16));
        s8v vf10 = *(const s8v*)(Vb + vrow1 + (((vc + hi)     ^ rswz) * 16));
        s8v vf11 = *(const s8v*)(Vb + vrow1 + (((vc + 2 + hi) ^ rswz) * 16));

        if (kv0s == qw0) {  // diagonal tile: keep iff kv row <= q col
#pragma unroll
          for (int r = 0; r < 16; ++r) {
            const int row = (r & 3) + 8 * (r >> 2) + 4 * hi;
            S[r] = (row <= l31) ? S[r] : -1e30f;
          }
        }
        float mloc = S[0];
#pragma unroll
        for (int r = 1; r < 16; ++r) mloc = fmaxf(mloc, S[r]);
        mloc = fmaxf(mloc, __shfl_xor(mloc, 32));
        if (__any(mloc > m_run + 8.f)) {   // defer-max (THR=8, exp2 domain)
          const float mnew = fmaxf(m_run, mloc);
          const float corr = fexp2(m_run - mnew);
          m_run = mnew;
          l_run *= corr;
#pragma unroll
          for (int r = 0; r < 16; ++r) { accO0[r] *= corr; accO1[r] *= corr; }
        }
        float p[16], sloc = 0.f;
#pragma unroll
        for (int r = 0; r < 16; ++r) {
          p[r] = fexp2(S[r] - m_run);
          sloc += p[r];
        }
        sloc += __shfl_xor(sloc, 32);
        l_run += sloc;

        const unsigned u0 = pk2bf(p[0],  p[1]),  u1 = pk2bf(p[2],  p[3]);
        const unsigned u2 = pk2bf(p[4],  p[5]),  u3 = pk2bf(p[6],  p[7]);
        const unsigned u4 = pk2bf(p[8],  p[9]),  u5 = pk2bf(p[10], p[11]);
        const unsigned u6 = pk2bf(p[12], p[13]), u7 = pk2bf(p[14], p[15]);
        const unsigned e0 = __shfl_xor(u0, 32), e1 = __shfl_xor(u1, 32);
        const unsigned e2 = __shfl_xor(u2, 32), e3 = __shfl_xor(u3, 32);
        const unsigned e4 = __shfl_xor(u4, 32), e5 = __shfl_xor(u5, 32);
        const unsigned e6 = __shfl_xor(u6, 32), e7 = __shfl_xor(u7, 32);
        const bool hih = (hi != 0);
        union { unsigned u[4]; s8v v; } P0, P1;
        P0.u[0] = hih ? e2 : u0;  P0.u[1] = hih ? e3 : u1;
        P0.u[2] = hih ? u2 : e0;  P0.u[3] = hih ? u3 : e1;
        P1.u[0] = hih ? e6 : u4;  P1.u[1] = hih ? e7 : u5;
        P1.u[2] = hih ? u6 : e4;  P1.u[3] = hih ? u7 : e5;

        accO0 = __builtin_amdgcn_mfma_f32_32x32x16_bf16(vf00, P0.v, accO0, 0, 0, 0);
        accO0 = __builtin_amdgcn_mfma_f32_32x32x16_bf16(vf01, P1.v, accO0, 0, 0, 0);
        accO1 = __builtin_amdgcn_mfma_f32_32x32x16_bf16(vf10, P0.v, accO1, 0, 0, 0);
        accO1 = __builtin_amdgcn_mfma_f32_32x32x16_bf16(vf11, P1.v, accO1, 0, 0, 0);
      }
    }
    if (t + 1 < nt) {  // write next tile into the other buffer
      char* nK = lds + (cur ^ 1) * 16384;
      *(s8v*)(nK + dK0) = k0;
      *(s8v*)(nK + dK1) = k1;
      *(s8v*)(nK + 8192 + dK0) = v0;
      *(s8v*)(nK + 8192 + dK1) = v1;
    }
    __syncthreads();
    cur ^= 1;
  }

  const float inv = 1.f / l_run;
  const int s = qw0 + l31;
  unsigned short* orow = obuf + (long)(b * SS + s) * HH + h * HDIM;
#pragma unroll
  for (int g = 0; g < 4; ++g) {
    const int d0 = 8 * g + 4 * hi;
    ushort4 o0, o1;
    o0.x = f2bf(accO0[4 * g + 0] * inv);
    o0.y = f2bf(accO0[4 * g + 1] * inv);
    o0.z = f2bf(accO0[4 * g + 2] * inv);
    o0.w = f2bf(accO0[4 * g + 3] * inv);
    o1.x = f2bf(accO1[4 * g + 0] * inv);
    o1.y = f2bf(accO1[4 * g + 1] * inv);
    o1.z = f2bf(accO1[4 * g + 2] * inv);
    o1.w = f2bf(accO1[4 * g + 3] * inv);
    *(ushort4*)(orow + d0)      = o0;
    *(ushort4*)(orow + 32 + d0) = o1;
  }
}

extern "C" void kernel_launch(void* const* d_in, const int* in_sizes, int n_in,
                              void* d_out, int out_size, void* d_ws, size_t ws_size,
                              hipStream_t stream) {
  const float* hs  = (const float*)d_in[0];
  const float* rot = (const float*)d_in[2];
  const float* wq  = (const float*)d_in[3];
  const float* wk  = (const float*)d_in[4];
  const float* wv  = (const float*)d_in[5];
  const float* wo  = (const float*)d_in[6];
  float* out = (float*)d_out;

  char* ws = (char*)d_ws;
  unsigned short* xb    = (unsigned short*)(ws + 0);          // 9,437,184
  unsigned short* wqkvt = (unsigned short*)(ws + 9437184);    // 1,105,920
  unsigned short* wot   = (unsigned short*)(ws + 10543104);   //   663,552
  unsigned short* qb    = (unsigned short*)(ws + 11206656);   // 9,437,184
  unsigned short* kb    = (unsigned short*)(ws + 20643840);   // 3,145,728
  unsigned short* vt    = (unsigned short*)(ws + 23789568);   // 3,145,728
  unsigned short* obuf  = (unsigned short*)(ws + 26935296);   // 9,437,184 -> 36,372,480

  cast_x_kernel<<<4608, 256, 0, stream>>>(hs, xb);
  pack_w_kernel<<<3456, 256, 0, stream>>>(wq, wk, wv, wo, wqkvt, wot);
  qkv_gemm_kernel<<<dim3(64, 15), 256, 0, stream>>>(xb, wqkvt, rot, qb, kb, vt);
  flash_lds_kernel<<<576, 256, 0, stream>>>(qb, kb, vt, obuf);
  out_gemm_kernel<<<dim3(64, 9), 256, 0, stream>>>(obuf, wot, out);
}